// Round 4
// baseline (128.253 us; speedup 1.0000x reference)
//
#include <hip/hip_runtime.h>

#define NT 2000
#define NB 256
#define NF 5
#define NS 500
#define LOG0   (-1e30f)
#define LOG2E  1.44269504088896340736f
#define LN2F   0.69314718055994530942f
#define RSTRIDE 2024   // wtabT row stride: >=2000, %4==0 (b128 align), %32==8 (banks disjoint)

// One block per batch, 512 threads = 8 waves, 2 states/lane.
// Wave w spans states [64w-64, 64w+127]: lanes 0-31 = 64-state left halo
// (recomputed redundantly), lanes 32-63 = 64 owned states. Halo depth 64 =
// exchange period 64 (info moves right 1 state/step).
//
// R4: SSA-rotated LDS double buffer. R3's VGPR=24 proved the compiler was
// NOT batching the 8 ds_read_b128 per chunk (needs 32 VGPRs of payload) ->
// an exposed ~100cy lgkmcnt wait every 2-3 steps was ~85% of main-loop time
// at 2 waves/SIMD. Now: issue chunk c+1's 8 loads into fresh locals BEFORE
// computing chunk c (sched_barrier(0) pins them above the compute), so the
// waitcnt pass emits a counted lgkmcnt(8) -- the prefetch stays in flight
// across the whole 16-step compute + boundary code. Single 8-float4 buffer
// + in-flight twin (~84 VGPR) -- unlike R2's 2x12 parity version (120 VGPR,
// allocator meltdown).
//
// Exp-domain recurrence p[s] += p[s-1]*w_t[idx[s]] with PER-LANE log2
// scale Lw. Cross-lane handoff via DPP wave_shr:1 (lane 0 gets 0).
// adj = 2^(Lw_left-Lw_self) folded into the W0 operand off the chain.
// Per-lane renorm every 16 steps; cross-wave exchange every 64 steps.
// XCD-swizzled batch id keeps the preamble gather dedup'd in per-XCD L2
// (FETCH 36MB -> 5.3MB, R2-verified).
__device__ __forceinline__ float wave_shr1(float v) {
    // DPP wave_shr:1 (0x138): lane i reads lane i-1; bound_ctrl=1 -> lane 0 = 0.
    return __int_as_float(
        __builtin_amdgcn_mov_dpp(__float_as_int(v), 0x138, 0xf, 0xf, true));
}

__global__ __launch_bounds__(512, 1) void ctc_fwd_kernel(
    const float* __restrict__ x,        // (NT, NB, NF)
    const int*   __restrict__ seqs,     // (NB, NS)
    const int*   __restrict__ seqlens,  // (NB,)
    float*       __restrict__ out)      // (NB,)
{
    __shared__ __align__(16) float wtabT[4 * RSTRIDE];  // w[i][t] = exp(x_t[i]-x_t[4])
    __shared__ float Gbuf[576];                         // log2-domain exchange, idx = 64+s
    __shared__ float red[512];                          // stay-sum reduction

    // XCD-aware batch swizzle: hw round-robins blockIdx%8 across XCDs;
    // map so XCD k handles contiguous b in [32k, 32k+32) for L2 line sharing.
    const int b    = ((blockIdx.x & 7) << 5) | (blockIdx.x >> 3);
    const int tid  = threadIdx.x;
    const int wave = tid >> 6;
    const int lane = tid & 63;

    // ---------------- precompute: transposed weights + stay sum ----------------
    float csum = 0.f;
    for (int t = tid; t < NT; t += 512) {
        const float* xp = x + (size_t)t * (NB * NF) + b * NF;
        const float x4 = xp[4];
        wtabT[0 * RSTRIDE + t] = __builtin_amdgcn_exp2f((xp[0] - x4) * LOG2E);
        wtabT[1 * RSTRIDE + t] = __builtin_amdgcn_exp2f((xp[1] - x4) * LOG2E);
        wtabT[2 * RSTRIDE + t] = __builtin_amdgcn_exp2f((xp[2] - x4) * LOG2E);
        wtabT[3 * RSTRIDE + t] = __builtin_amdgcn_exp2f((xp[3] - x4) * LOG2E);
        csum += x4;
    }
    for (int i = tid; i < 576; i += 512) Gbuf[i] = LOG0;
    red[tid] = csum;
    __syncthreads();
    for (int off = 256; off > 0; off >>= 1) {
        if (tid < off) red[tid] += red[tid + off];
        __syncthreads();
    }
    // red[0] = C = sum over t of x_t[4]

    // ---------------- per-lane setup ----------------
    const int wbase = wave * 64 - 64;
    const int rel0 = 2 * lane;                 // 0..126; owned iff rel0 >= 64
    const int s0 = wbase + rel0, s1 = s0 + 1;
    const bool owned = (rel0 >= 64);

    const int i0 = (s0 >= 1 && s0 <= NS) ? seqs[b * NS + s0 - 1] : 0;
    const int i1 = (s1 >= 1 && s1 <= NS) ? seqs[b * NS + s1 - 1] : 0;
    const float* wrow0 = &wtabT[i0 * RSTRIDE];
    const float* wrow1 = &wtabT[i1 * RSTRIDE];

    float p0 = (s0 == 0) ? 1.f : 0.f;
    float p1 = (s1 == 0) ? 1.f : 0.f;
    float Lw  = 0.f;   // per-lane log2 offset
    float adj = 1.f;   // 2^(Lw_left - Lw_self), refreshed after every renorm/exchange

    // W0A already contains the adj factor (folded off the dependent chain).
#define STEP(W0A, W1) do {                    \
        const float sh = wave_shr1(p1);       \
        p1 = fmaf(p0, (W1), p1);              \
        p0 = fmaf(sh, (W0A), p0);             \
    } while (0)

#define QSTEP(WA, WB) do {                    \
        STEP(WA.x * adj, WB.x);               \
        STEP(WA.y * adj, WB.y);               \
        STEP(WA.z * adj, WB.z);               \
        STEP(WA.w * adj, WB.w);               \
    } while (0)

    // ---------------- main loop: 125 chunks of 16 steps ----------------
    // Prime the pipeline: chunk 0's weights into the carried registers.
    float4 ca0 = *reinterpret_cast<const float4*>(wrow0);
    float4 ca1 = *reinterpret_cast<const float4*>(wrow0 + 4);
    float4 ca2 = *reinterpret_cast<const float4*>(wrow0 + 8);
    float4 ca3 = *reinterpret_cast<const float4*>(wrow0 + 12);
    float4 cb0 = *reinterpret_cast<const float4*>(wrow1);
    float4 cb1 = *reinterpret_cast<const float4*>(wrow1 + 4);
    float4 cb2 = *reinterpret_cast<const float4*>(wrow1 + 8);
    float4 cb3 = *reinterpret_cast<const float4*>(wrow1 + 12);

    for (int c = 0; c < 125; ++c) {
        if (c > 0) {
            if ((c & 3) == 0) {
                // ---- cross-wave exchange every 64 steps (log2 domain) ----
                __syncthreads();
                if (owned) {
                    Gbuf[64 + s0] = (p0 > 0.f) ? __builtin_amdgcn_logf(p0) + Lw : LOG0;
                    Gbuf[64 + s1] = (p1 > 0.f) ? __builtin_amdgcn_logf(p1) + Lw : LOG0;
                }
                __syncthreads();
                const float g0 = Gbuf[64 + s0];
                const float g1 = Gbuf[64 + s1];
                const float ref = fmaxf(g0, g1);
                const bool alive = (ref > 0.5f * LOG0);
                // live states form a prefix of the window -> last live lane is
                // nearest-live-left for all dead lanes. Uniform mask -> scalar ops.
                const unsigned long long mk = __ballot(alive);
                float fb = 0.f;
                if (mk) {
                    const int lastlive = 63 - __builtin_clzll(mk);
                    fb = __int_as_float(
                        __builtin_amdgcn_readlane(__float_as_int(ref), lastlive));
                }
                Lw = alive ? ref : fb;
                p0 = __builtin_amdgcn_exp2f(g0 - Lw);   // dead: exp2(-1e30)=0
                p1 = __builtin_amdgcn_exp2f(g1 - Lw);
            } else {
                // ---- per-lane renorm every 16 steps ----
                const float m = fmaxf(p0, p1);
                if (m > 0.f) {
                    const float inv = __builtin_amdgcn_rcpf(m);
                    Lw += __builtin_amdgcn_logf(m);     // v_log_f32 = log2
                    p0 *= inv; p1 *= inv;
                }
            }
            const float Lwp = wave_shr1(Lw);            // lane 0: Lwp=0; its sh inflow is 0 anyway
            adj = __builtin_amdgcn_exp2f(fminf(Lwp - Lw, 100.f));
        }

        // ---- issue NEXT chunk's 8 ds_read_b128 (fresh SSA locals) ----
        // c==124: dummy reload of chunk 0 (in-bounds, discarded) keeps the
        // loop body branch-free and wave-uniform.
        const int tbn = (c < 124) ? ((c + 1) << 4) : 0;
        const float4 na0 = *reinterpret_cast<const float4*>(wrow0 + tbn);
        const float4 na1 = *reinterpret_cast<const float4*>(wrow0 + tbn + 4);
        const float4 na2 = *reinterpret_cast<const float4*>(wrow0 + tbn + 8);
        const float4 na3 = *reinterpret_cast<const float4*>(wrow0 + tbn + 12);
        const float4 nb0 = *reinterpret_cast<const float4*>(wrow1 + tbn);
        const float4 nb1 = *reinterpret_cast<const float4*>(wrow1 + tbn + 4);
        const float4 nb2 = *reinterpret_cast<const float4*>(wrow1 + tbn + 8);
        const float4 nb3 = *reinterpret_cast<const float4*>(wrow1 + tbn + 12);
        // Pin the loads above the compute: without this the scheduler sinks
        // them toward their (next-iteration) position and re-dribbles them.
        __builtin_amdgcn_sched_barrier(0);

        // ---- compute current chunk entirely from carried registers ----
        QSTEP(ca0, cb0);
        QSTEP(ca1, cb1);
        QSTEP(ca2, cb2);
        QSTEP(ca3, cb3);

        // carry (coalesces into PHIs; no LDS waits here)
        ca0 = na0; ca1 = na1; ca2 = na2; ca3 = na3;
        cb0 = nb0; cb1 = nb1; cb2 = nb2; cb3 = nb3;
    }
#undef QSTEP
#undef STEP

    // ---------------- final write-out ----------------
    __syncthreads();
    if (owned) {
        Gbuf[64 + s0] = (p0 > 0.f) ? __builtin_amdgcn_logf(p0) + Lw : LOG0;
        Gbuf[64 + s1] = (p1 > 0.f) ? __builtin_amdgcn_logf(p1) + Lw : LOG0;
    }
    __syncthreads();
    if (tid == 0) {
        const int sl = seqlens[b];
        out[b] = -(Gbuf[64 + sl] * LN2F + red[0]) * (1.0f / (float)NT);
    }
}

extern "C" void kernel_launch(void* const* d_in, const int* in_sizes, int n_in,
                              void* d_out, int out_size, void* d_ws, size_t ws_size,
                              hipStream_t stream) {
    const float* x       = (const float*)d_in[0];
    const int*   seqs    = (const int*)d_in[1];
    const int*   seqlens = (const int*)d_in[2];
    float*       out     = (float*)d_out;

    ctc_fwd_kernel<<<dim3(NB), dim3(512), 0, stream>>>(x, seqs, seqlens, out);
}

// Round 5
// 126.882 us; speedup vs baseline: 1.0108x; 1.0108x over previous
//
#include <hip/hip_runtime.h>

#define NT 2000
#define NB 256
#define NF 5
#define NS 500
#define LOG0   (-1e30f)
#define LOG2E  1.44269504088896340736f
#define LN2F   0.69314718055994530942f
#define RSH 2024   // f16 row stride (elements): >=2000, %8==0 (b128-aligned rows),
                   // 4048B rows put the 4 rows at bank offsets {0,20,8,28} -> disjoint

// One block per batch, 512 threads = 8 waves, 2 states/lane.
// Wave w spans states [64w-64, 64w+127]: lanes 0-31 = 64-state left halo
// (recomputed redundantly), lanes 32-63 = 64 owned states. Halo depth 64 =
// exchange period 64 (info moves right 1 state/step).
//
// R5: f16 weight table. R3 vs R4 showed the wall is LDS *throughput*, not
// latency: 8 waves x 8 ds_read_b128 per 16-step chunk = 64 wave-wide reads
// per chunk per CU (~10cy each on the shared LDS pipe) ~= 40 cy/step --
// prefetching (R4) couldn't help a saturated pipe. f16 halves the read
// count (8 weights per b128): 32 reads/chunk/CU. Unpack folds into
// v_fma_mix / one full-rate cvt. Weight range exp(+-10) fits f16; the
// ~5e-4 relative noise is a random walk ~0.013 nats over 2000 steps,
// /NT at the output -> ~7e-6 absolute, invisible.
//
// Exp-domain recurrence p[s] += p[s-1]*w_t[idx[s]] with PER-LANE log2
// scale Lw. Cross-lane handoff via DPP wave_shr:1 (lane 0 gets 0).
// adj = 2^(Lw_left-Lw_self) folded into the W0 operand off the chain.
// Per-lane renorm every 16 steps; cross-wave exchange every 64 steps.
// XCD-swizzled batch id keeps the preamble gather dedup'd in per-XCD L2
// (FETCH 36MB -> 5.3MB, R2-verified).
typedef _Float16 half8 __attribute__((ext_vector_type(8)));

__device__ __forceinline__ float wave_shr1(float v) {
    // DPP wave_shr:1 (0x138): lane i reads lane i-1; bound_ctrl=1 -> lane 0 = 0.
    return __int_as_float(
        __builtin_amdgcn_mov_dpp(__float_as_int(v), 0x138, 0xf, 0xf, true));
}

__global__ __launch_bounds__(512, 1) void ctc_fwd_kernel(
    const float* __restrict__ x,        // (NT, NB, NF)
    const int*   __restrict__ seqs,     // (NB, NS)
    const int*   __restrict__ seqlens,  // (NB,)
    float*       __restrict__ out)      // (NB,)
{
    __shared__ __align__(16) _Float16 wtabT[4 * RSH];   // w[i][t] = exp(x_t[i]-x_t[4]), f16
    __shared__ float Gbuf[576];                         // log2-domain exchange, idx = 64+s
    __shared__ float red[512];                          // stay-sum reduction

    // XCD-aware batch swizzle: hw round-robins blockIdx%8 across XCDs;
    // map so XCD k handles contiguous b in [32k, 32k+32) for L2 line sharing.
    const int b    = ((blockIdx.x & 7) << 5) | (blockIdx.x >> 3);
    const int tid  = threadIdx.x;
    const int wave = tid >> 6;
    const int lane = tid & 63;

    // ---------------- precompute: transposed f16 weights + stay sum ----------------
    float csum = 0.f;
    for (int t = tid; t < NT; t += 512) {
        const float* xp = x + (size_t)t * (NB * NF) + b * NF;
        const float x4 = xp[4];
        wtabT[0 * RSH + t] = (_Float16)__builtin_amdgcn_exp2f((xp[0] - x4) * LOG2E);
        wtabT[1 * RSH + t] = (_Float16)__builtin_amdgcn_exp2f((xp[1] - x4) * LOG2E);
        wtabT[2 * RSH + t] = (_Float16)__builtin_amdgcn_exp2f((xp[2] - x4) * LOG2E);
        wtabT[3 * RSH + t] = (_Float16)__builtin_amdgcn_exp2f((xp[3] - x4) * LOG2E);
        csum += x4;
    }
    for (int i = tid; i < 576; i += 512) Gbuf[i] = LOG0;
    red[tid] = csum;
    __syncthreads();
    for (int off = 256; off > 0; off >>= 1) {
        if (tid < off) red[tid] += red[tid + off];
        __syncthreads();
    }
    // red[0] = C = sum over t of x_t[4]

    // ---------------- per-lane setup ----------------
    const int wbase = wave * 64 - 64;
    const int rel0 = 2 * lane;                 // 0..126; owned iff rel0 >= 64
    const int s0 = wbase + rel0, s1 = s0 + 1;
    const bool owned = (rel0 >= 64);

    const int i0 = (s0 >= 1 && s0 <= NS) ? seqs[b * NS + s0 - 1] : 0;
    const int i1 = (s1 >= 1 && s1 <= NS) ? seqs[b * NS + s1 - 1] : 0;
    const _Float16* wrow0 = &wtabT[i0 * RSH];
    const _Float16* wrow1 = &wtabT[i1 * RSH];

    float p0 = (s0 == 0) ? 1.f : 0.f;
    float p1 = (s1 == 0) ? 1.f : 0.f;
    float Lw  = 0.f;   // per-lane log2 offset
    float adj = 1.f;   // 2^(Lw_left - Lw_self), refreshed after every renorm/exchange

    // W0A already contains the adj factor (folded off the dependent chain).
#define STEP(W0A, W1) do {                    \
        const float sh = wave_shr1(p1);       \
        p1 = fmaf(p0, (W1), p1);              \
        p0 = fmaf(sh, (W0A), p0);             \
    } while (0)

    // One step from f16 vectors, element K (compile-time constant index).
#define HSTEP(AV, BV, K) STEP((float)(AV)[K] * adj, (float)(BV)[K])

#define HOCT(AV, BV) do {                     \
        HSTEP(AV, BV, 0); HSTEP(AV, BV, 1);   \
        HSTEP(AV, BV, 2); HSTEP(AV, BV, 3);   \
        HSTEP(AV, BV, 4); HSTEP(AV, BV, 5);   \
        HSTEP(AV, BV, 6); HSTEP(AV, BV, 7);   \
    } while (0)

    // ---------------- main loop: 125 chunks of 16 steps ----------------
    for (int c = 0; c < 125; ++c) {
        if (c > 0) {
            if ((c & 3) == 0) {
                // ---- cross-wave exchange every 64 steps (log2 domain) ----
                __syncthreads();
                if (owned) {
                    Gbuf[64 + s0] = (p0 > 0.f) ? __builtin_amdgcn_logf(p0) + Lw : LOG0;
                    Gbuf[64 + s1] = (p1 > 0.f) ? __builtin_amdgcn_logf(p1) + Lw : LOG0;
                }
                __syncthreads();
                const float g0 = Gbuf[64 + s0];
                const float g1 = Gbuf[64 + s1];
                const float ref = fmaxf(g0, g1);
                const bool alive = (ref > 0.5f * LOG0);
                // live states form a prefix of the window -> last live lane is
                // nearest-live-left for all dead lanes. Uniform mask -> scalar ops.
                const unsigned long long mk = __ballot(alive);
                float fb = 0.f;
                if (mk) {
                    const int lastlive = 63 - __builtin_clzll(mk);
                    fb = __int_as_float(
                        __builtin_amdgcn_readlane(__float_as_int(ref), lastlive));
                }
                Lw = alive ? ref : fb;
                p0 = __builtin_amdgcn_exp2f(g0 - Lw);   // dead: exp2(-1e30)=0
                p1 = __builtin_amdgcn_exp2f(g1 - Lw);
            } else {
                // ---- per-lane renorm every 16 steps ----
                const float m = fmaxf(p0, p1);
                if (m > 0.f) {
                    const float inv = __builtin_amdgcn_rcpf(m);
                    Lw += __builtin_amdgcn_logf(m);     // v_log_f32 = log2
                    p0 *= inv; p1 *= inv;
                }
            }
            const float Lwp = wave_shr1(Lw);            // lane 0: Lwp=0; its sh inflow is 0 anyway
            adj = __builtin_amdgcn_exp2f(fminf(Lwp - Lw, 100.f));
        }
        const int tb = c << 4;
        {
            // 4 ds_read_b128 per chunk (was 8 in f32): 8 weights each.
            const half8 a0 = *reinterpret_cast<const half8*>(wrow0 + tb);
            const half8 a1 = *reinterpret_cast<const half8*>(wrow0 + tb + 8);
            const half8 b0 = *reinterpret_cast<const half8*>(wrow1 + tb);
            const half8 b1 = *reinterpret_cast<const half8*>(wrow1 + tb + 8);
            HOCT(a0, b0);
            HOCT(a1, b1);
        }
    }
#undef HOCT
#undef HSTEP
#undef STEP

    // ---------------- final write-out ----------------
    __syncthreads();
    if (owned) {
        Gbuf[64 + s0] = (p0 > 0.f) ? __builtin_amdgcn_logf(p0) + Lw : LOG0;
        Gbuf[64 + s1] = (p1 > 0.f) ? __builtin_amdgcn_logf(p1) + Lw : LOG0;
    }
    __syncthreads();
    if (tid == 0) {
        const int sl = seqlens[b];
        out[b] = -(Gbuf[64 + sl] * LN2F + red[0]) * (1.0f / (float)NT);
    }
}

extern "C" void kernel_launch(void* const* d_in, const int* in_sizes, int n_in,
                              void* d_out, int out_size, void* d_ws, size_t ws_size,
                              hipStream_t stream) {
    const float* x       = (const float*)d_in[0];
    const int*   seqs    = (const int*)d_in[1];
    const int*   seqlens = (const int*)d_in[2];
    float*       out     = (float*)d_out;

    ctc_fwd_kernel<<<dim3(NB), dim3(512), 0, stream>>>(x, seqs, seqlens, out);
}

// Round 6
// 119.175 us; speedup vs baseline: 1.0762x; 1.0647x over previous
//
#include <hip/hip_runtime.h>

#define NT 2000
#define NB 256
#define NF 5
#define NS 500
#define LOG0   (-1e30f)
#define LOG2E  1.44269504088896340736f
#define LN2F   0.69314718055994530942f
#define RSTRIDE 2024   // wtabT row stride: >=2000, %4==0 (b128 align), %32==8 (banks disjoint)

// One block per batch, 512 threads = 8 waves, 2 states/lane.
// Wave w spans states [64w-64, 64w+127]: lanes 0-31 = 64-state left halo
// (recomputed redundantly), lanes 32-63 = 64 owned states. Halo depth 64 =
// exchange period 64 (info moves right 1 state/step).
//
// R6: the R4/R5 experiments falsified the LDS-latency and LDS-throughput
// theories (prefetch regressed; halving reads via f16 regressed). The
// kernel is VALU-issue + boundary-serialization bound. This round:
//  (a) CONDITIONAL renorm: the per-chunk rcp/log/exp2+DPP chain (~60-100cy
//      serial, gating the next chunk via adj) runs only when any lane's
//      magnitude leaves [1e-12, 1e12]. Wave-uniform branch; typical drift
//      is ~5 nats/16 steps so it almost never fires; when skipped, no Lw
//      changes anywhere in the wave, so adj stays valid. Dead lanes (m==0)
//      don't trigger. Worst realistic 16-step drift (~e^40) keeps values
//      inside f32 range from these thresholds.
//  (b) hoist the chunk's 8 ds_read_b128 above the boundary code (hides
//      their latency under boundary work; no copies, no double buffer).
//  (c) f32 weight table restored (R3 form; f16 cvts cost more than the
//      reads they saved).
// This structure is the op-minimum of its family: 1 batch/CU forced,
// >=2 waves/SIMD needs 8 waves, 8 waves forces 2 states/lane.
//
// Exp-domain recurrence p[s] += p[s-1]*w_t[idx[s]] with PER-LANE log2
// scale Lw. Cross-lane handoff via DPP wave_shr:1 (lane 0 gets 0).
// adj = 2^(Lw_left-Lw_self) folded into the W0 operand off the chain.
// Cross-wave exchange (log2 domain via Gbuf) every 64 steps. XCD-swizzled
// batch id keeps the preamble gather dedup'd in per-XCD L2 (FETCH
// 36MB -> 5.3MB, R2-verified).
__device__ __forceinline__ float wave_shr1(float v) {
    // DPP wave_shr:1 (0x138): lane i reads lane i-1; bound_ctrl=1 -> lane 0 = 0.
    return __int_as_float(
        __builtin_amdgcn_mov_dpp(__float_as_int(v), 0x138, 0xf, 0xf, true));
}

__global__ __launch_bounds__(512, 1) void ctc_fwd_kernel(
    const float* __restrict__ x,        // (NT, NB, NF)
    const int*   __restrict__ seqs,     // (NB, NS)
    const int*   __restrict__ seqlens,  // (NB,)
    float*       __restrict__ out)      // (NB,)
{
    __shared__ __align__(16) float wtabT[4 * RSTRIDE];  // w[i][t] = exp(x_t[i]-x_t[4])
    __shared__ float Gbuf[576];                         // log2-domain exchange, idx = 64+s
    __shared__ float red[512];                          // stay-sum reduction

    // XCD-aware batch swizzle: hw round-robins blockIdx%8 across XCDs;
    // map so XCD k handles contiguous b in [32k, 32k+32) for L2 line sharing.
    const int b    = ((blockIdx.x & 7) << 5) | (blockIdx.x >> 3);
    const int tid  = threadIdx.x;
    const int wave = tid >> 6;
    const int lane = tid & 63;

    // ---------------- precompute: transposed weights + stay sum ----------------
    float csum = 0.f;
    for (int t = tid; t < NT; t += 512) {
        const float* xp = x + (size_t)t * (NB * NF) + b * NF;
        const float x4 = xp[4];
        wtabT[0 * RSTRIDE + t] = __builtin_amdgcn_exp2f((xp[0] - x4) * LOG2E);
        wtabT[1 * RSTRIDE + t] = __builtin_amdgcn_exp2f((xp[1] - x4) * LOG2E);
        wtabT[2 * RSTRIDE + t] = __builtin_amdgcn_exp2f((xp[2] - x4) * LOG2E);
        wtabT[3 * RSTRIDE + t] = __builtin_amdgcn_exp2f((xp[3] - x4) * LOG2E);
        csum += x4;
    }
    for (int i = tid; i < 576; i += 512) Gbuf[i] = LOG0;
    red[tid] = csum;
    __syncthreads();
    for (int off = 256; off > 0; off >>= 1) {
        if (tid < off) red[tid] += red[tid + off];
        __syncthreads();
    }
    // red[0] = C = sum over t of x_t[4]

    // ---------------- per-lane setup ----------------
    const int wbase = wave * 64 - 64;
    const int rel0 = 2 * lane;                 // 0..126; owned iff rel0 >= 64
    const int s0 = wbase + rel0, s1 = s0 + 1;
    const bool owned = (rel0 >= 64);

    const int i0 = (s0 >= 1 && s0 <= NS) ? seqs[b * NS + s0 - 1] : 0;
    const int i1 = (s1 >= 1 && s1 <= NS) ? seqs[b * NS + s1 - 1] : 0;
    const float* wrow0 = &wtabT[i0 * RSTRIDE];
    const float* wrow1 = &wtabT[i1 * RSTRIDE];

    float p0 = (s0 == 0) ? 1.f : 0.f;
    float p1 = (s1 == 0) ? 1.f : 0.f;
    float Lw  = 0.f;   // per-lane log2 offset
    float adj = 1.f;   // 2^(Lw_left - Lw_self), refreshed after every renorm/exchange

    // W0A already contains the adj factor (folded off the dependent chain).
#define STEP(W0A, W1) do {                    \
        const float sh = wave_shr1(p1);       \
        p1 = fmaf(p0, (W1), p1);              \
        p0 = fmaf(sh, (W0A), p0);             \
    } while (0)

#define QSTEP(WA, WB) do {                    \
        STEP(WA.x * adj, WB.x);               \
        STEP(WA.y * adj, WB.y);               \
        STEP(WA.z * adj, WB.z);               \
        STEP(WA.w * adj, WB.w);               \
    } while (0)

    // ---------------- main loop: 125 chunks of 16 steps ----------------
    for (int c = 0; c < 125; ++c) {
        // Issue the chunk's 8 ds_read_b128 FIRST: their latency hides under
        // the boundary code below (renorm test / exchange), zero extra state.
        const int tb = c << 4;
        const float4 a0 = *reinterpret_cast<const float4*>(wrow0 + tb);
        const float4 a1 = *reinterpret_cast<const float4*>(wrow0 + tb + 4);
        const float4 a2 = *reinterpret_cast<const float4*>(wrow0 + tb + 8);
        const float4 a3 = *reinterpret_cast<const float4*>(wrow0 + tb + 12);
        const float4 b0 = *reinterpret_cast<const float4*>(wrow1 + tb);
        const float4 b1 = *reinterpret_cast<const float4*>(wrow1 + tb + 4);
        const float4 b2 = *reinterpret_cast<const float4*>(wrow1 + tb + 8);
        const float4 b3 = *reinterpret_cast<const float4*>(wrow1 + tb + 12);

        if (c > 0) {
            if ((c & 3) == 0) {
                // ---- cross-wave exchange every 64 steps (log2 domain) ----
                __syncthreads();
                if (owned) {
                    Gbuf[64 + s0] = (p0 > 0.f) ? __builtin_amdgcn_logf(p0) + Lw : LOG0;
                    Gbuf[64 + s1] = (p1 > 0.f) ? __builtin_amdgcn_logf(p1) + Lw : LOG0;
                }
                __syncthreads();
                const float g0 = Gbuf[64 + s0];
                const float g1 = Gbuf[64 + s1];
                const float ref = fmaxf(g0, g1);
                const bool alive = (ref > 0.5f * LOG0);
                // live states form a prefix of the window -> last live lane is
                // nearest-live-left for all dead lanes. Uniform mask -> scalar ops.
                const unsigned long long mk = __ballot(alive);
                float fb = 0.f;
                if (mk) {
                    const int lastlive = 63 - __builtin_clzll(mk);
                    fb = __int_as_float(
                        __builtin_amdgcn_readlane(__float_as_int(ref), lastlive));
                }
                Lw = alive ? ref : fb;
                p0 = __builtin_amdgcn_exp2f(g0 - Lw);   // dead: exp2(-1e30)=0
                p1 = __builtin_amdgcn_exp2f(g1 - Lw);
                const float Lwp = wave_shr1(Lw);        // lane 0: Lwp=0; its sh inflow is 0 anyway
                adj = __builtin_amdgcn_exp2f(fminf(Lwp - Lw, 100.f));
            } else {
                // ---- renorm only when some live lane leaves safe range ----
                const float m = fmaxf(p0, p1);
                const bool bad = (m > 1e12f) || (m > 0.f && m < 1e-12f);
                if (__any(bad)) {
                    // wave-uniform: ALL lanes renorm together, so every Lw
                    // that changes gets a matching adj refresh below.
                    if (m > 0.f) {
                        const float inv = __builtin_amdgcn_rcpf(m);
                        Lw += __builtin_amdgcn_logf(m); // v_log_f32 = log2
                        p0 *= inv; p1 *= inv;
                    }
                    const float Lwp = wave_shr1(Lw);
                    adj = __builtin_amdgcn_exp2f(fminf(Lwp - Lw, 100.f));
                }
                // skipped: no Lw changed anywhere in the wave -> adj still valid
            }
        }

        QSTEP(a0, b0);
        QSTEP(a1, b1);
        QSTEP(a2, b2);
        QSTEP(a3, b3);
    }
#undef QSTEP
#undef STEP

    // ---------------- final write-out ----------------
    __syncthreads();
    if (owned) {
        Gbuf[64 + s0] = (p0 > 0.f) ? __builtin_amdgcn_logf(p0) + Lw : LOG0;
        Gbuf[64 + s1] = (p1 > 0.f) ? __builtin_amdgcn_logf(p1) + Lw : LOG0;
    }
    __syncthreads();
    if (tid == 0) {
        const int sl = seqlens[b];
        out[b] = -(Gbuf[64 + sl] * LN2F + red[0]) * (1.0f / (float)NT);
    }
}

extern "C" void kernel_launch(void* const* d_in, const int* in_sizes, int n_in,
                              void* d_out, int out_size, void* d_ws, size_t ws_size,
                              hipStream_t stream) {
    const float* x       = (const float*)d_in[0];
    const int*   seqs    = (const int*)d_in[1];
    const int*   seqlens = (const int*)d_in[2];
    float*       out     = (float*)d_out;

    ctc_fwd_kernel<<<dim3(NB), dim3(512), 0, stream>>>(x, seqs, seqlens, out);
}